// Round 8
// baseline (184.130 us; speedup 1.0000x reference)
//
#include <hip/hip_runtime.h>
#include <math.h>

#define NB 512
#define NN 64
#define TL 657
#define LV1 328
#define LV2 164
#define LV3 82
#define LV4 41
#define HID 82
#define ST 66      // padded LDS stride for 64x64 matrices

// workspace byte offsets (aliased by liveness)
#define WS_M      0          // 2*4096 f32
#define WS_ACC    32768      // 512 doubles
#define WS_SMEAN  36864
#define WS_SMAX   167936
#define WS_FC2T   299008     // 82*657 f32 -> ends 514504 (pad 514560)
#define WS_CSUM   682496     // 512*657 f32 -> ends 2028032
#define WS_CMAX   2028032    // -> ends 3373568
#define WS_CATT   3373568    // -> ends 4719104
#define WS_Y1     682496     // 512*64*32 f32 (aliases csum/cmax/catt; dead by gcn1) ends 4876800
#define WS_DELTA  4876800    // 512*64*41 f32 -> ends 10250752
#define WS_Y2     4876800    // aliases delta (dead by gcn2)
#define WS_OUT1   5925376    // 512*32 f32

// accumulator (double) indices
#define ACC_Y1 0
#define ACC_Y2 64
#define ACC_O1 80

__device__ __forceinline__ float sigmoidf_(float v){ return 1.0f/(1.0f+expf(-v)); }

__device__ __forceinline__ void wav_level(float* __restrict__ dst, const float* __restrict__ src,
                                          int outL, int inL, int lane){
  const float DLO[8] = {0.23037781330885523f, 0.7148465705525415f, 0.6308807679295904f,
                        -0.02798376941698385f, -0.18703481171888114f, 0.030841381835986965f,
                        0.032883011666982945f, -0.010597401784997278f};
  for (int k=lane; k<outL; k+=64){
    int i0 = 2*k - 3;
    float a = 0.f;
    #pragma unroll
    for (int j=0;j<8;j++){
      int idx = i0 + j;
      idx = (idx < 0) ? idx + inL : ((idx >= inL) ? idx - inL : idx);
      a += src[idx]*DLO[j];
    }
    dst[k] = a;
  }
}

// 64x64 matmul, 8 waves (512 threads), wave wv does rows [8wv,8wv+8).
__device__ __forceinline__ void mm8(float* __restrict__ D, int dstride,
                                    const float* __restrict__ A, const float* __restrict__ Bm){
  int tid = threadIdx.x;
  int wv = tid >> 6, lane = tid & 63;
  int i0 = wv*8;
  float acc8[8];
  #pragma unroll
  for (int i=0;i<8;i++) acc8[i]=0.f;
  #pragma unroll
  for (int kc=0; kc<4; kc++){
    float bb[16];
    #pragma unroll
    for (int j=0;j<16;j++) bb[j] = Bm[(kc*16+j)*ST + lane];
    #pragma unroll
    for (int i=0;i<8;i++){
      const float2* ar = (const float2*)&A[(i0+i)*ST + kc*16];
      float s0=0.f, s1=0.f;
      #pragma unroll
      for (int j2=0;j2<8;j2++){
        float2 v = ar[j2];
        s0 += v.x*bb[2*j2]; s1 += v.y*bb[2*j2+1];
      }
      acc8[i] += s0+s1;
    }
  }
  #pragma unroll
  for (int i=0;i<8;i++) D[(i0+i)*dstride + lane] = acc8[i];
}

// ---------------- fused front: row-streaming channel stats (blocks 0..511)
// ----------------   + graph prep (512,513) + fc2 transpose (514..521). 512 threads.
__global__ __launch_bounds__(512) void k_front(
    const float* __restrict__ x,
    const float* __restrict__ lgw, const float* __restrict__ gmask,
    const float* __restrict__ tril, const int* __restrict__ edges,
    const float* __restrict__ fc2,
    float* __restrict__ csum, float* __restrict__ cmax,
    float* __restrict__ Mout, float* __restrict__ fc2T,
    double* __restrict__ acc)
{
  __shared__ float smem[3*NN*ST];   // 12672 floats: graph bufs / merge bufs / transpose tile
  __shared__ float deg[64], hs[64], dinv[64], wself[64];
  int tid = threadIdx.x;
  int bid = blockIdx.x;

  if (bid < NB){
    // ---- channel stats, streaming: wave wv streams rows 8wv..8wv+7 ----
    int b = bid;
    int wv = tid>>6, lane = tid&63;
    float s[11], m[11];
    #pragma unroll
    for (int i=0;i<11;i++){ s[i]=0.f; m[i]=-INFINITY; }
    const float* xb = x + (size_t)b*NN*TL;
    for (int r=0;r<8;r++){
      const float* row = xb + (size_t)(wv*8 + r)*TL;
      #pragma unroll
      for (int i=0;i<11;i++){
        int t = lane + 64*i;
        if (t < TL){
          float v = row[t];
          s[i] += v; m[i] = fmaxf(m[i], v);
        }
      }
    }
    // tree merge of 8 wave-partials via LDS (4 double-buffers of 2x664)
    float* buf = smem;
    for (int step=4; step>=1; step>>=1){
      if (wv >= step && wv < 2*step){
        float* bs = buf + (wv-step)*2*664;
        #pragma unroll
        for (int i=0;i<11;i++){
          int t = lane + 64*i;
          if (t<TL){ bs[t] = s[i]; bs[664+t] = m[i]; }
        }
      }
      __syncthreads();
      if (wv < step){
        float* bs = buf + wv*2*664;
        #pragma unroll
        for (int i=0;i<11;i++){
          int t = lane + 64*i;
          if (t<TL){ s[i] += bs[t]; m[i] = fmaxf(m[i], bs[664+t]); }
        }
      }
      __syncthreads();
    }
    if (wv==0){
      #pragma unroll
      for (int i=0;i<11;i++){
        int t = lane + 64*i;
        if (t<TL){
          csum[(size_t)b*TL + t] = s[i];
          cmax[(size_t)b*TL + t] = m[i];
        }
      }
    }
    return;
  }

  int gi = bid - NB;    // 0..9
  if (gi >= 2){
    // ---- tiled transpose of fc2 (657x82) -> fc2T (82x657) ----
    int t8 = gi - 2;      // 0..7
    int r0 = t8*83;
    int rn = (t8==7) ? (TL - 7*83) : 83;
    for (int i=tid; i<rn*HID; i+=512){
      int r = i / HID, u = i - r*HID;
      smem[u*85 + r] = fc2[(size_t)r0*HID + i];
    }
    __syncthreads();
    for (int j=tid; j<HID*83; j+=512){
      int u = j / 83, c = j - u*83;
      if (c < rn) fc2T[u*TL + r0 + c] = smem[u*85 + c];
    }
    return;
  }

  // ---- graph prep: g=0 local, g=1 global ----
  float* Wbuf = smem;
  float* Amat = smem + NN*ST;
  float* P1   = smem + 2*NN*ST;
  int g = gi;
  if (g==0 && tid<512) acc[tid]=0.0;
  for (int e=tid;e<4096;e+=512){
    float w;
    if (g==0) w = lgw[e];
    else {
      int i=e>>6, j=e&63;
      int aa = (i>j)? i:j, bb = (i>j)? j:i;
      w = tril[aa*(aa+1)/2 + bb] * gmask[e];
    }
    Wbuf[e] = w;
  }
  for (int i=tid;i<NN*ST;i+=512) Amat[i] = 0.f;
  if (tid<64){ deg[tid]=0.f; hs[tid]=0.f; }
  __syncthreads();
  {
    int e0 = tid*8;
    int runr = edges[e0];
    float runv = 0.f;
    #pragma unroll 4
    for (int i=0;i<8;i++){
      int e = e0+i;
      int r = edges[e];
      int c = edges[4096+e];
      float w = Wbuf[e];
      if (r != runr){ atomicAdd(&deg[runr], runv); runr = r; runv = 0.f; }
      runv += fabsf(w);
      if (r == c) hs[r] = 1.f;
    }
    atomicAdd(&deg[runr], runv);
  }
  __syncthreads();
  if (tid<64){
    float w_ = (hs[tid] > 0.f) ? 0.f : 1.f;
    float d = deg[tid] + w_;
    dinv[tid] = (d > 0.f) ? rsqrtf(d) : 0.f;
    wself[tid] = w_;
  }
  __syncthreads();
  for (int e=tid;e<4096;e+=512){
    int r = edges[e], c = edges[4096+e];
    float nm = dinv[r]*Wbuf[e]*dinv[c];
    atomicAdd(&Amat[c*ST+r], nm);
  }
  __syncthreads();
  if (tid<64) Amat[tid*ST+tid] += dinv[tid]*wself[tid]*dinv[tid];
  __syncthreads();
  mm8(P1,   ST, Amat, Amat); __syncthreads();   // A^2
  mm8(Wbuf, ST, P1,   P1);   __syncthreads();   // A^4
  mm8(&Mout[g*4096], 64, Wbuf, Amat);           // A^5
}

// ---------------- fused MLP (both layers) -> catt: grid 512, 512 threads ----------------
__global__ __launch_bounds__(512) void k_mlp(
    const float* __restrict__ csum, const float* __restrict__ cmax,
    const float* __restrict__ fc1, const float* __restrict__ fc2T,
    float* __restrict__ catt)
{
  __shared__ float cs[TL], cm[TL];
  __shared__ float h[HID];
  int tid = threadIdx.x, b = blockIdx.x;
  for (int i=tid;i<TL;i+=512){
    cs[i] = csum[(size_t)b*TL + i];
    cm[i] = cmax[(size_t)b*TL + i];
  }
  __syncthreads();
  int wv = tid>>6, lane = tid&63;
  for (int o=wv; o<HID; o+=8){
    const float* fr = fc1 + (size_t)o*TL;
    float a = 0.f, bm = 0.f;
    #pragma unroll
    for (int i=0;i<11;i++){
      int c = lane + 64*i;
      if (c < TL){
        float f = fr[c];
        a += f*cs[c]; bm += f*cm[c];
      }
    }
    #pragma unroll
    for (int off=32;off;off>>=1){
      a  += __shfl_xor(a,off);
      bm += __shfl_xor(bm,off);
    }
    if (lane==0)
      h[o] = fmaxf(a*(1.0f/64.0f),0.f) + fmaxf(bm,0.f);
  }
  __syncthreads();
  for (int c=tid;c<TL;c+=512){
    float a=0.f;
    #pragma unroll 4
    for (int u=0;u<HID;u++) a += fc2T[(size_t)u*TL + c]*h[u];
    catt[(size_t)b*TL + c] = sigmoidf_(a);
  }
}

// ---------------- wavelet cascade + spatial stats: grid (512,16), one row per wave ----------------
__global__ __launch_bounds__(256) void k_wav(
    const float* __restrict__ x, const float* __restrict__ catt_g,
    float* __restrict__ delta, float* __restrict__ smean, float* __restrict__ smax)
{
  __shared__ float catt[TL];
  __shared__ float yb[4][TL];
  __shared__ float o1b[4][LV1];
  __shared__ float o2b[4][LV2];
  __shared__ float o3b[4][LV3];
  int tid = threadIdx.x, b = blockIdx.x;
  for (int i=tid;i<TL;i+=256) catt[i] = catt_g[(size_t)b*TL + i];
  __syncthreads();
  int wv = tid>>6, lane = tid&63;
  int n = blockIdx.y*4 + wv;
  float* y  = yb[wv];
  float* p1 = o1b[wv];
  float* p2 = o2b[wv];
  float* p3 = o3b[wv];
  const float DLO[8] = {0.23037781330885523f, 0.7148465705525415f, 0.6308807679295904f,
                        -0.02798376941698385f, -0.18703481171888114f, 0.030841381835986965f,
                        0.032883011666982945f, -0.010597401784997278f};
  const float* row = x + ((size_t)b*NN + n)*TL;
  float ls = 0.f, lm = -INFINITY;
  #pragma unroll
  for (int i=0;i<11;i++){
    int t = lane + 64*i;
    if (t < TL){
      float v = row[t]*catt[t];
      y[t] = v; ls += v; lm = fmaxf(lm,v);
    }
  }
  #pragma unroll
  for (int off=32;off;off>>=1){
    ls += __shfl_xor(ls,off);
    lm = fmaxf(lm, __shfl_xor(lm,off));
  }
  if (lane==0){ smean[b*NN+n] = ls*(1.0f/657.0f); smax[b*NN+n] = lm; }
  wav_level(p1, y,  LV1, TL,  lane);
  wav_level(p2, p1, LV2, LV1, lane);
  wav_level(p3, p2, LV3, LV2, lane);
  if (lane < LV4){
    int i0 = 2*lane - 3;
    float a = 0.f;
    #pragma unroll
    for (int j=0;j<8;j++){
      int idx = i0 + j;
      idx = (idx < 0) ? idx + LV3 : ((idx >= LV3) ? idx - LV3 : idx);
      a += p3[idx]*DLO[j];
    }
    delta[((size_t)b*NN + n)*LV4 + lane] = a;
  }
}

// ---------------- GCN block 1 (+ fused spatial attention scale) ----------------
__global__ __launch_bounds__(256) void k_gcn1(
  const float* __restrict__ delta, const float* __restrict__ Mmat,
  const float* __restrict__ smean, const float* __restrict__ smax,
  const float* __restrict__ saw,
  const float* __restrict__ ldW, const float* __restrict__ ldb,
  const float* __restrict__ dW, const float* __restrict__ db2,
  float* __restrict__ Y1, double* __restrict__ acc)
{
  __shared__ float Dl[NN*LV4];
  __shared__ float Tt[NN*16];
  __shared__ float Mm[4096];
  __shared__ float Wl[16*LV4];
  __shared__ float satt[NN];
  __shared__ double red[256];
  int tid=threadIdx.x, b=blockIdx.x;
  if (tid < NN){
    float a = 0.f;
    #pragma unroll
    for (int kw=0;kw<7;kw++){
      int w = tid + kw - 3;
      if (0<=w && w<NN) a += smean[b*NN+w]*saw[21+kw] + smax[b*NN+w]*saw[70+kw];
    }
    satt[tid] = sigmoidf_(a);
  }
  __syncthreads();
  const float* ds = delta + (size_t)b*NN*LV4;
  for (int i=tid;i<NN*LV4;i+=256) Dl[i] = ds[i]*satt[i/LV4];
  for (int g=0; g<2; g++){
    const float* Ws = g ? dW : ldW;
    const float* bs = g ? db2 : ldb;
    for (int i=tid;i<16*LV4;i+=256) Wl[i]=Ws[i];
    for (int i=tid;i<4096;i+=256) Mm[i]=Mmat[g*4096+i];
    __syncthreads();
    for (int e=tid;e<NN*16;e+=256){
      int n=e>>4, o=e&15;
      const float* dr=&Dl[n*LV4];
      const float* wr=&Wl[o*LV4];
      float a=0.f;
      #pragma unroll 8
      for (int c=0;c<LV4;c++) a += dr[c]*wr[c];
      Tt[e]=a;
    }
    __syncthreads();
    float bias = bs[tid&15];
    float ps=0.f, pq=0.f;
    for (int m=0;m<4;m++){
      int e=tid+256*m;
      int n=e>>4, o=e&15;
      float a=bias;
      #pragma unroll 8
      for (int k=0;k<64;k++) a += Mm[n*64+k]*Tt[k*16+o];
      Y1[((size_t)b*NN+n)*32 + g*16 + o] = a;
      ps += a; pq += a*a;
    }
    red[tid]=(double)ps;
    __syncthreads();
    if (tid<16){ double t=0; for (int r=tid;r<256;r+=16) t+=red[r]; atomicAdd(&acc[ACC_Y1+g*32+tid], t); }
    __syncthreads();
    red[tid]=(double)pq;
    __syncthreads();
    if (tid<16){ double t=0; for (int r=tid;r<256;r+=16) t+=red[r]; atomicAdd(&acc[ACC_Y1+g*32+16+tid], t); }
    __syncthreads();
  }
}

// ---------------- GCN block 2 ----------------
__global__ __launch_bounds__(256) void k_gcn2(
  const float* __restrict__ Y1, const float* __restrict__ Mmat,
  const float* __restrict__ ldg, const float* __restrict__ ldbe,
  const float* __restrict__ dg, const float* __restrict__ dbe,
  const float* __restrict__ ld1W, const float* __restrict__ ld1b,
  const float* __restrict__ d1W, const float* __restrict__ d1b,
  float* __restrict__ Y2, double* __restrict__ acc)
{
  __shared__ float Yl[NN*32];
  __shared__ float T2[NN*8];
  __shared__ float Mm[2*4096];
  __shared__ float scl[32], sht[32];
  __shared__ double red[256];
  int tid=threadIdx.x, b=blockIdx.x;
  const float* ys = Y1 + (size_t)b*NN*32;
  for (int i=tid;i<NN*32;i+=256) Yl[i]=ys[i];
  for (int i=tid;i<8192;i+=256) Mm[i]=Mmat[i];
  if (tid<32){
    int g=tid>>4, o=tid&15;
    double s=acc[ACC_Y1+g*32+o], q=acc[ACC_Y1+g*32+16+o];
    double mean=s/32768.0;
    double var=q/32768.0 - mean*mean;
    float gam = g? dg[o] : ldg[o];
    float bet = g? dbe[o] : ldbe[o];
    float sc = gam * rsqrtf((float)var + 1e-5f);
    scl[tid]=sc; sht[tid]=bet - (float)mean*sc;
  }
  __syncthreads();
  for (int i=tid;i<NN*32;i+=256){ int c=i&31; Yl[i]=Yl[i]*scl[c]+sht[c]; }
  __syncthreads();
  for (int e=tid;e<NN*8;e+=256){
    int n=e>>3, c=e&7, g=c>>2, p=c&3;
    const float* w = (g? d1W : ld1W) + p*16;
    const float* yr = &Yl[n*32 + g*16];
    float a=0.f;
    #pragma unroll
    for (int o=0;o<16;o++) a += yr[o]*w[o];
    T2[e]=a;
  }
  __syncthreads();
  float ps=0.f,pq=0.f;
  for (int m=0;m<2;m++){
    int e=tid+256*m;
    int n=e>>3, c=e&7, g=c>>2;
    float a = g? d1b[c&3] : ld1b[c&3];
    const float* mr=&Mm[g*4096+n*64];
    #pragma unroll 8
    for (int k=0;k<64;k++) a += mr[k]*T2[k*8+c];
    Y2[((size_t)b*NN+n)*8 + c] = a;
    ps+=a; pq+=a*a;
  }
  red[tid]=(double)ps; __syncthreads();
  if (tid<8){ double t=0; for (int r=tid;r<256;r+=8) t+=red[r]; atomicAdd(&acc[ACC_Y2 + (tid>>2)*8 + (tid&3)], t); }
  __syncthreads();
  red[tid]=(double)pq; __syncthreads();
  if (tid<8){ double t=0; for (int r=tid;r<256;r+=8) t+=red[r]; atomicAdd(&acc[ACC_Y2 + (tid>>2)*8 + 4 + (tid&3)], t); }
}

// ---------------- BN(Y2) -> feat -> cls layer1 ----------------
__global__ __launch_bounds__(64) void k_featcls(
  const float* __restrict__ Y2,
  const float* __restrict__ ld1g, const float* __restrict__ ld1be,
  const float* __restrict__ d1g, const float* __restrict__ d1be,
  const float* __restrict__ W1, const float* __restrict__ b1,
  float* __restrict__ out1, double* __restrict__ acc)
{
  __shared__ float f[128];
  __shared__ float scl[8], sht[8];
  int tid=threadIdx.x, b=blockIdx.x;
  if (tid<8){
    int g=tid>>2, p=tid&3;
    double s=acc[ACC_Y2+g*8+p], q=acc[ACC_Y2+g*8+4+p];
    double mean=s/32768.0;
    double var=q/32768.0-mean*mean;
    float gam = g? d1g[p]:ld1g[p];
    float bet = g? d1be[p]:ld1be[p];
    float sc = gam*rsqrtf((float)var+1e-5f);
    scl[tid]=sc; sht[tid]=bet-(float)mean*sc;
  }
  __syncthreads();
  {
    const float* yr = Y2 + ((size_t)b*NN+tid)*8;
    float lf=0.f, gf=0.f;
    #pragma unroll
    for (int p=0;p<4;p++){
      lf += yr[p]*scl[p]+sht[p];
      gf += yr[4+p]*scl[4+p]+sht[4+p];
    }
    f[2*tid]   = lf*0.25f;
    f[2*tid+1] = gf*0.25f;
  }
  __syncthreads();
  if (tid<32){
    const float* w = W1 + tid*128;
    float a = b1[tid];
    #pragma unroll 4
    for (int m=0;m<128;m++) a += w[m]*f[m];
    out1[b*32+tid]=a;
    atomicAdd(&acc[ACC_O1+tid], (double)a);
    atomicAdd(&acc[ACC_O1+32+tid], (double)(a*a));
  }
}

// ---------------- BN(out1) -> cls layer2 -> log_softmax ----------------
__global__ __launch_bounds__(64) void k_cls2(
  const float* __restrict__ out1,
  const float* __restrict__ cg, const float* __restrict__ cbe,
  const float* __restrict__ W2, const float* __restrict__ b2,
  const double* __restrict__ acc, float* __restrict__ out)
{
  __shared__ float v[32];
  __shared__ float z[2];
  int tid=threadIdx.x, b=blockIdx.x;
  if (tid<32){
    double s=acc[ACC_O1+tid], q=acc[ACC_O1+32+tid];
    double mean=s/512.0;
    double var=q/512.0-mean*mean;
    float sc=cg[tid]*rsqrtf((float)var+1e-5f);
    float sh=cbe[tid]-(float)mean*sc;
    v[tid]=out1[b*32+tid]*sc+sh;
  }
  __syncthreads();
  if (tid<2){
    const float* w=W2+tid*32;
    float a=b2[tid];
    #pragma unroll
    for (int j=0;j<32;j++) a += w[j]*v[j];
    z[tid]=a;
  }
  __syncthreads();
  if (tid<2){
    float m=fmaxf(z[0],z[1]);
    float l=m+logf(expf(z[0]-m)+expf(z[1]-m));
    out[b*2+tid]=z[tid]-l;
  }
}

extern "C" void kernel_launch(void* const* d_in, const int* in_sizes, int n_in,
                              void* d_out, int out_size, void* d_ws, size_t ws_size,
                              hipStream_t stream) {
  (void)in_sizes; (void)n_in; (void)out_size; (void)ws_size;
  const float* x     = (const float*)d_in[0];
  const float* lgw   = (const float*)d_in[1];
  const float* gmask = (const float*)d_in[2];
  const float* fc1   = (const float*)d_in[3];
  const float* fc2   = (const float*)d_in[4];
  const float* saw   = (const float*)d_in[5];
  const float* tril  = (const float*)d_in[6];
  const float* ldW   = (const float*)d_in[7];
  const float* ldb   = (const float*)d_in[8];
  const float* ldg   = (const float*)d_in[9];
  const float* ldbe  = (const float*)d_in[10];
  const float* ld1W  = (const float*)d_in[11];
  const float* ld1b  = (const float*)d_in[12];
  const float* ld1g  = (const float*)d_in[13];
  const float* ld1be = (const float*)d_in[14];
  const float* dW    = (const float*)d_in[15];
  const float* db2   = (const float*)d_in[16];
  const float* dg    = (const float*)d_in[17];
  const float* dbe   = (const float*)d_in[18];
  const float* d1W   = (const float*)d_in[19];
  const float* d1b   = (const float*)d_in[20];
  const float* d1g   = (const float*)d_in[21];
  const float* d1be  = (const float*)d_in[22];
  const float* cW1   = (const float*)d_in[23];
  const float* cb1   = (const float*)d_in[24];
  const float* cgam  = (const float*)d_in[25];
  const float* cbet  = (const float*)d_in[26];
  const float* cW2   = (const float*)d_in[27];
  const float* cb2   = (const float*)d_in[28];
  const int*   edges = (const int*)d_in[29];

  char* ws = (char*)d_ws;
  float*  M     = (float*)(ws + WS_M);
  double* acc   = (double*)(ws + WS_ACC);
  float*  smean = (float*)(ws + WS_SMEAN);
  float*  smax  = (float*)(ws + WS_SMAX);
  float*  fc2T  = (float*)(ws + WS_FC2T);
  float*  csum  = (float*)(ws + WS_CSUM);
  float*  cmax  = (float*)(ws + WS_CMAX);
  float*  catt  = (float*)(ws + WS_CATT);
  float*  Y1    = (float*)(ws + WS_Y1);
  float*  delta = (float*)(ws + WS_DELTA);
  float*  Y2    = (float*)(ws + WS_Y2);
  float*  out1  = (float*)(ws + WS_OUT1);
  float*  out   = (float*)d_out;

  k_front<<<NB + 10, 512, 0, stream>>>(x, lgw, gmask, tril, edges, fc2,
                                       csum, cmax, M, fc2T, acc);
  k_mlp<<<NB, 512, 0, stream>>>(csum, cmax, fc1, fc2T, catt);
  k_wav<<<dim3(NB, 16), 256, 0, stream>>>(x, catt, delta, smean, smax);
  k_gcn1<<<NB, 256, 0, stream>>>(delta, M, smean, smax, saw, ldW, ldb, dW, db2, Y1, acc);
  k_gcn2<<<NB, 256, 0, stream>>>(Y1, M, ldg, ldbe, dg, dbe, ld1W, ld1b, d1W, d1b, Y2, acc);
  k_featcls<<<NB, 64, 0, stream>>>(Y2, ld1g, ld1be, d1g, d1be, cW1, cb1, out1, acc);
  k_cls2<<<NB, 64, 0, stream>>>(out1, cgam, cbet, cW2, cb2, acc, out);
}

// Round 9
// 162.840 us; speedup vs baseline: 1.1307x; 1.1307x over previous
//
#include <hip/hip_runtime.h>
#include <math.h>

#define NB 512
#define NN 64
#define TL 657
#define LV1 328
#define LV2 164
#define LV3 82
#define LV4 41
#define HID 82
#define ST 66      // padded LDS stride for 64x64 matrices

// workspace byte offsets (aliased by liveness)
#define WS_M      0          // 2*4096 f32
#define WS_ACC    32768      // 512 doubles
#define WS_SMEAN  36864
#define WS_SMAX   167936
#define WS_CATT   3373568    // 512*657 f32 -> ends 4719104
#define WS_Y1     682496     // 512*64*32 f32 (dead by gcn2 writeback) ends 4876800
#define WS_DELTA  4876800    // 512*64*41 f32 -> ends 10250752
#define WS_Y2     4876800    // aliases delta (dead by gcn2)
#define WS_OUT1   5925376    // 512*32 f32

// accumulator (double) indices
#define ACC_Y1 0
#define ACC_Y2 64
#define ACC_O1 80

__device__ __forceinline__ float sigmoidf_(float v){ return 1.0f/(1.0f+expf(-v)); }

__device__ __forceinline__ void wav_level(float* __restrict__ dst, const float* __restrict__ src,
                                          int outL, int inL, int lane){
  const float DLO[8] = {0.23037781330885523f, 0.7148465705525415f, 0.6308807679295904f,
                        -0.02798376941698385f, -0.18703481171888114f, 0.030841381835986965f,
                        0.032883011666982945f, -0.010597401784997278f};
  for (int k=lane; k<outL; k+=64){
    int i0 = 2*k - 3;
    float a = 0.f;
    #pragma unroll
    for (int j=0;j<8;j++){
      int idx = i0 + j;
      idx = (idx < 0) ? idx + inL : ((idx >= inL) ? idx - inL : idx);
      a += src[idx]*DLO[j];
    }
    dst[k] = a;
  }
}

// 64x64 matmul, 16 waves (1024 threads), wave wv does rows [4wv,4wv+4).
__device__ __forceinline__ void mm16(float* __restrict__ D, int dstride,
                                     const float* __restrict__ A, const float* __restrict__ Bm){
  int tid = threadIdx.x;
  int wv = tid >> 6, lane = tid & 63;
  int i0 = wv*4;
  float a4[4] = {0.f,0.f,0.f,0.f};
  #pragma unroll
  for (int kc=0; kc<4; kc++){
    float bb[16];
    #pragma unroll
    for (int j=0;j<16;j++) bb[j] = Bm[(kc*16+j)*ST + lane];
    #pragma unroll
    for (int i=0;i<4;i++){
      const float2* ar = (const float2*)&A[(i0+i)*ST + kc*16];
      float s0=0.f, s1=0.f;
      #pragma unroll
      for (int j2=0;j2<8;j2++){
        float2 v = ar[j2];
        s0 += v.x*bb[2*j2]; s1 += v.y*bb[2*j2+1];
      }
      a4[i] += s0+s1;
    }
  }
  #pragma unroll
  for (int i=0;i<4;i++) D[(i0+i)*dstride + lane] = a4[i];
}

// ---------------- fused front, 1024 threads:
//   bid 0,1   : graph prep (runs from t=0, overlapped with stats)
//   bid 2..513: per-batch channel stats + full CBAM channel-MLP -> catt
__global__ __launch_bounds__(1024) void k_front(
    const float* __restrict__ x,
    const float* __restrict__ lgw, const float* __restrict__ gmask,
    const float* __restrict__ tril, const int* __restrict__ edges,
    const float* __restrict__ fc1, const float* __restrict__ fc2,
    float* __restrict__ catt_g,
    float* __restrict__ Mout, double* __restrict__ acc)
{
  __shared__ float smem[3*NN*ST];   // 12672 floats: graph bufs / stats merge + cs/cm/h
  __shared__ float deg[64], hs[64], dinv[64], wself[64];
  int tid = threadIdx.x;
  int bid = blockIdx.x;
  int wv = tid>>6, lane = tid&63;

  if (bid >= 2){
    // ---- channel stats: wave wv streams rows 4wv..4wv+3 ----
    int b = bid - 2;
    float s[11], m[11];
    #pragma unroll
    for (int i=0;i<11;i++){ s[i]=0.f; m[i]=-INFINITY; }
    const float* xb = x + (size_t)b*NN*TL;
    for (int r=0;r<4;r++){
      const float* row = xb + (size_t)(wv*4 + r)*TL;
      #pragma unroll
      for (int i=0;i<11;i++){
        int t = lane + 64*i;
        if (t < TL){
          float v = row[t];
          s[i] += v; m[i] = fmaxf(m[i], v);
        }
      }
    }
    // tree merge of 16 wave-partials (slots of 1328 floats)
    for (int step=8; step>=1; step>>=1){
      if (wv >= step && wv < 2*step){
        float* bs = smem + (wv-step)*1328;
        #pragma unroll
        for (int i=0;i<11;i++){
          int t = lane + 64*i;
          if (t<TL){ bs[t] = s[i]; bs[664+t] = m[i]; }
        }
      }
      __syncthreads();
      if (wv < step){
        float* bs = smem + wv*1328;
        #pragma unroll
        for (int i=0;i<11;i++){
          int t = lane + 64*i;
          if (t<TL){ s[i] += bs[t]; m[i] = fmaxf(m[i], bs[664+t]); }
        }
      }
      __syncthreads();
    }
    // wave0 publishes final cs/cm
    float* cs = smem;          // [657]
    float* cm = smem + 664;    // [657]
    float* h  = smem + 1400;   // [82]
    if (wv==0){
      #pragma unroll
      for (int i=0;i<11;i++){
        int t = lane + 64*i;
        if (t<TL){ cs[t] = s[i]; cm[t] = m[i]; }
      }
    }
    __syncthreads();
    // MLP layer 1: wave per output row of fc1 (coalesced)
    for (int o=wv; o<HID; o+=16){
      const float* fr = fc1 + (size_t)o*TL;
      float a = 0.f, bm = 0.f;
      #pragma unroll
      for (int i=0;i<11;i++){
        int c = lane + 64*i;
        if (c < TL){
          float f = fr[c];
          a += f*cs[c]; bm += f*cm[c];
        }
      }
      #pragma unroll
      for (int off=32;off;off>>=1){
        a  += __shfl_xor(a,off);
        bm += __shfl_xor(bm,off);
      }
      if (lane==0)
        h[o] = fmaxf(a*(1.0f/64.0f),0.f) + fmaxf(bm,0.f);
    }
    __syncthreads();
    // MLP layer 2: thread per output channel c, fc2 row contiguous (float2)
    if (tid < TL){
      const float2* fr = (const float2*)(fc2 + (size_t)tid*HID);
      float a0=0.f, a1=0.f;
      #pragma unroll
      for (int u2=0;u2<41;u2++){
        float2 v = fr[u2];
        a0 += v.x*h[2*u2]; a1 += v.y*h[2*u2+1];
      }
      catt_g[(size_t)b*TL + tid] = sigmoidf_(a0+a1);
    }
    return;
  }

  // ---- graph prep: g=0 local, g=1 global ----
  float* Wbuf = smem;
  float* Amat = smem + NN*ST;
  float* P1   = smem + 2*NN*ST;
  int g = bid;
  if (g==0 && tid<512) acc[tid]=0.0;
  for (int e=tid;e<4096;e+=1024){
    float w;
    if (g==0) w = lgw[e];
    else {
      int i=e>>6, j=e&63;
      int aa = (i>j)? i:j, bb = (i>j)? j:i;
      w = tril[aa*(aa+1)/2 + bb] * gmask[e];
    }
    Wbuf[e] = w;
  }
  for (int i=tid;i<NN*ST;i+=1024) Amat[i] = 0.f;
  if (tid<64){ deg[tid]=0.f; hs[tid]=0.f; }
  __syncthreads();
  {
    int e0 = tid*4;
    int runr = edges[e0];
    float runv = 0.f;
    #pragma unroll
    for (int i=0;i<4;i++){
      int e = e0+i;
      int r = edges[e];
      int c = edges[4096+e];
      float w = Wbuf[e];
      if (r != runr){ atomicAdd(&deg[runr], runv); runr = r; runv = 0.f; }
      runv += fabsf(w);
      if (r == c) hs[r] = 1.f;
    }
    atomicAdd(&deg[runr], runv);
  }
  __syncthreads();
  if (tid<64){
    float w_ = (hs[tid] > 0.f) ? 0.f : 1.f;
    float d = deg[tid] + w_;
    dinv[tid] = (d > 0.f) ? rsqrtf(d) : 0.f;
    wself[tid] = w_;
  }
  __syncthreads();
  for (int e=tid;e<4096;e+=1024){
    int r = edges[e], c = edges[4096+e];
    float nm = dinv[r]*Wbuf[e]*dinv[c];
    atomicAdd(&Amat[c*ST+r], nm);
  }
  __syncthreads();
  if (tid<64) Amat[tid*ST+tid] += dinv[tid]*wself[tid]*dinv[tid];
  __syncthreads();
  mm16(P1,   ST, Amat, Amat); __syncthreads();   // A^2
  mm16(Wbuf, ST, P1,   P1);   __syncthreads();   // A^4
  mm16(&Mout[g*4096], 64, Wbuf, Amat);           // A^5
}

// ---------------- wavelet cascade + spatial stats: grid (512,16), one row per wave ----------------
__global__ __launch_bounds__(256) void k_wav(
    const float* __restrict__ x, const float* __restrict__ catt_g,
    float* __restrict__ delta, float* __restrict__ smean, float* __restrict__ smax)
{
  __shared__ float catt[TL];
  __shared__ float yb[4][TL];
  __shared__ float o1b[4][LV1];
  __shared__ float o2b[4][LV2];
  __shared__ float o3b[4][LV3];
  int tid = threadIdx.x, b = blockIdx.x;
  for (int i=tid;i<TL;i+=256) catt[i] = catt_g[(size_t)b*TL + i];
  __syncthreads();
  int wv = tid>>6, lane = tid&63;
  int n = blockIdx.y*4 + wv;
  float* y  = yb[wv];
  float* p1 = o1b[wv];
  float* p2 = o2b[wv];
  float* p3 = o3b[wv];
  const float DLO[8] = {0.23037781330885523f, 0.7148465705525415f, 0.6308807679295904f,
                        -0.02798376941698385f, -0.18703481171888114f, 0.030841381835986965f,
                        0.032883011666982945f, -0.010597401784997278f};
  const float* row = x + ((size_t)b*NN + n)*TL;
  float ls = 0.f, lm = -INFINITY;
  #pragma unroll
  for (int i=0;i<11;i++){
    int t = lane + 64*i;
    if (t < TL){
      float v = row[t]*catt[t];
      y[t] = v; ls += v; lm = fmaxf(lm,v);
    }
  }
  #pragma unroll
  for (int off=32;off;off>>=1){
    ls += __shfl_xor(ls,off);
    lm = fmaxf(lm, __shfl_xor(lm,off));
  }
  if (lane==0){ smean[b*NN+n] = ls*(1.0f/657.0f); smax[b*NN+n] = lm; }
  wav_level(p1, y,  LV1, TL,  lane);
  wav_level(p2, p1, LV2, LV1, lane);
  wav_level(p3, p2, LV3, LV2, lane);
  if (lane < LV4){
    int i0 = 2*lane - 3;
    float a = 0.f;
    #pragma unroll
    for (int j=0;j<8;j++){
      int idx = i0 + j;
      idx = (idx < 0) ? idx + LV3 : ((idx >= LV3) ? idx - LV3 : idx);
      a += p3[idx]*DLO[j];
    }
    delta[((size_t)b*NN + n)*LV4 + lane] = a;
  }
}

// ---------------- GCN block 1 (+ fused spatial attention scale) ----------------
__global__ __launch_bounds__(256) void k_gcn1(
  const float* __restrict__ delta, const float* __restrict__ Mmat,
  const float* __restrict__ smean, const float* __restrict__ smax,
  const float* __restrict__ saw,
  const float* __restrict__ ldW, const float* __restrict__ ldb,
  const float* __restrict__ dW, const float* __restrict__ db2,
  float* __restrict__ Y1, double* __restrict__ acc)
{
  __shared__ float Dl[NN*LV4];
  __shared__ float Tt[NN*16];
  __shared__ float Mm[4096];
  __shared__ float Wl[16*LV4];
  __shared__ float satt[NN];
  __shared__ double red[256];
  int tid=threadIdx.x, b=blockIdx.x;
  if (tid < NN){
    float a = 0.f;
    #pragma unroll
    for (int kw=0;kw<7;kw++){
      int w = tid + kw - 3;
      if (0<=w && w<NN) a += smean[b*NN+w]*saw[21+kw] + smax[b*NN+w]*saw[70+kw];
    }
    satt[tid] = sigmoidf_(a);
  }
  __syncthreads();
  const float* ds = delta + (size_t)b*NN*LV4;
  for (int i=tid;i<NN*LV4;i+=256) Dl[i] = ds[i]*satt[i/LV4];
  for (int g=0; g<2; g++){
    const float* Ws = g ? dW : ldW;
    const float* bs = g ? db2 : ldb;
    for (int i=tid;i<16*LV4;i+=256) Wl[i]=Ws[i];
    for (int i=tid;i<4096;i+=256) Mm[i]=Mmat[g*4096+i];
    __syncthreads();
    for (int e=tid;e<NN*16;e+=256){
      int n=e>>4, o=e&15;
      const float* dr=&Dl[n*LV4];
      const float* wr=&Wl[o*LV4];
      float a=0.f;
      #pragma unroll 8
      for (int c=0;c<LV4;c++) a += dr[c]*wr[c];
      Tt[e]=a;
    }
    __syncthreads();
    float bias = bs[tid&15];
    float ps=0.f, pq=0.f;
    for (int m=0;m<4;m++){
      int e=tid+256*m;
      int n=e>>4, o=e&15;
      float a=bias;
      #pragma unroll 8
      for (int k=0;k<64;k++) a += Mm[n*64+k]*Tt[k*16+o];
      Y1[((size_t)b*NN+n)*32 + g*16 + o] = a;
      ps += a; pq += a*a;
    }
    red[tid]=(double)ps;
    __syncthreads();
    if (tid<16){ double t=0; for (int r=tid;r<256;r+=16) t+=red[r]; atomicAdd(&acc[ACC_Y1+g*32+tid], t); }
    __syncthreads();
    red[tid]=(double)pq;
    __syncthreads();
    if (tid<16){ double t=0; for (int r=tid;r<256;r+=16) t+=red[r]; atomicAdd(&acc[ACC_Y1+g*32+16+tid], t); }
    __syncthreads();
  }
}

// ---------------- GCN block 2 ----------------
__global__ __launch_bounds__(256) void k_gcn2(
  const float* __restrict__ Y1, const float* __restrict__ Mmat,
  const float* __restrict__ ldg, const float* __restrict__ ldbe,
  const float* __restrict__ dg, const float* __restrict__ dbe,
  const float* __restrict__ ld1W, const float* __restrict__ ld1b,
  const float* __restrict__ d1W, const float* __restrict__ d1b,
  float* __restrict__ Y2, double* __restrict__ acc)
{
  __shared__ float Yl[NN*32];
  __shared__ float T2[NN*8];
  __shared__ float Mm[2*4096];
  __shared__ float scl[32], sht[32];
  __shared__ double red[256];
  int tid=threadIdx.x, b=blockIdx.x;
  const float* ys = Y1 + (size_t)b*NN*32;
  for (int i=tid;i<NN*32;i+=256) Yl[i]=ys[i];
  for (int i=tid;i<8192;i+=256) Mm[i]=Mmat[i];
  if (tid<32){
    int g=tid>>4, o=tid&15;
    double s=acc[ACC_Y1+g*32+o], q=acc[ACC_Y1+g*32+16+o];
    double mean=s/32768.0;
    double var=q/32768.0 - mean*mean;
    float gam = g? dg[o] : ldg[o];
    float bet = g? dbe[o] : ldbe[o];
    float sc = gam * rsqrtf((float)var + 1e-5f);
    scl[tid]=sc; sht[tid]=bet - (float)mean*sc;
  }
  __syncthreads();
  for (int i=tid;i<NN*32;i+=256){ int c=i&31; Yl[i]=Yl[i]*scl[c]+sht[c]; }
  __syncthreads();
  for (int e=tid;e<NN*8;e+=256){
    int n=e>>3, c=e&7, g=c>>2, p=c&3;
    const float* w = (g? d1W : ld1W) + p*16;
    const float* yr = &Yl[n*32 + g*16];
    float a=0.f;
    #pragma unroll
    for (int o=0;o<16;o++) a += yr[o]*w[o];
    T2[e]=a;
  }
  __syncthreads();
  float ps=0.f,pq=0.f;
  for (int m=0;m<2;m++){
    int e=tid+256*m;
    int n=e>>3, c=e&7, g=c>>2;
    float a = g? d1b[c&3] : ld1b[c&3];
    const float* mr=&Mm[g*4096+n*64];
    #pragma unroll 8
    for (int k=0;k<64;k++) a += mr[k]*T2[k*8+c];
    Y2[((size_t)b*NN+n)*8 + c] = a;
    ps+=a; pq+=a*a;
  }
  red[tid]=(double)ps; __syncthreads();
  if (tid<8){ double t=0; for (int r=tid;r<256;r+=8) t+=red[r]; atomicAdd(&acc[ACC_Y2 + (tid>>2)*8 + (tid&3)], t); }
  __syncthreads();
  red[tid]=(double)pq; __syncthreads();
  if (tid<8){ double t=0; for (int r=tid;r<256;r+=8) t+=red[r]; atomicAdd(&acc[ACC_Y2 + (tid>>2)*8 + 4 + (tid&3)], t); }
}

// ---------------- BN(Y2) -> feat -> cls layer1 ----------------
__global__ __launch_bounds__(64) void k_featcls(
  const float* __restrict__ Y2,
  const float* __restrict__ ld1g, const float* __restrict__ ld1be,
  const float* __restrict__ d1g, const float* __restrict__ d1be,
  const float* __restrict__ W1, const float* __restrict__ b1,
  float* __restrict__ out1, double* __restrict__ acc)
{
  __shared__ float f[128];
  __shared__ float scl[8], sht[8];
  int tid=threadIdx.x, b=blockIdx.x;
  if (tid<8){
    int g=tid>>2, p=tid&3;
    double s=acc[ACC_Y2+g*8+p], q=acc[ACC_Y2+g*8+4+p];
    double mean=s/32768.0;
    double var=q/32768.0-mean*mean;
    float gam = g? d1g[p]:ld1g[p];
    float bet = g? d1be[p]:ld1be[p];
    float sc = gam*rsqrtf((float)var+1e-5f);
    scl[tid]=sc; sht[tid]=bet-(float)mean*sc;
  }
  __syncthreads();
  {
    const float* yr = Y2 + ((size_t)b*NN+tid)*8;
    float lf=0.f, gf=0.f;
    #pragma unroll
    for (int p=0;p<4;p++){
      lf += yr[p]*scl[p]+sht[p];
      gf += yr[4+p]*scl[4+p]+sht[4+p];
    }
    f[2*tid]   = lf*0.25f;
    f[2*tid+1] = gf*0.25f;
  }
  __syncthreads();
  if (tid<32){
    const float* w = W1 + tid*128;
    float a = b1[tid];
    #pragma unroll 4
    for (int m=0;m<128;m++) a += w[m]*f[m];
    out1[b*32+tid]=a;
    atomicAdd(&acc[ACC_O1+tid], (double)a);
    atomicAdd(&acc[ACC_O1+32+tid], (double)(a*a));
  }
}

// ---------------- BN(out1) -> cls layer2 -> log_softmax ----------------
__global__ __launch_bounds__(64) void k_cls2(
  const float* __restrict__ out1,
  const float* __restrict__ cg, const float* __restrict__ cbe,
  const float* __restrict__ W2, const float* __restrict__ b2,
  const double* __restrict__ acc, float* __restrict__ out)
{
  __shared__ float v[32];
  __shared__ float z[2];
  int tid=threadIdx.x, b=blockIdx.x;
  if (tid<32){
    double s=acc[ACC_O1+tid], q=acc[ACC_O1+32+tid];
    double mean=s/512.0;
    double var=q/512.0-mean*mean;
    float sc=cg[tid]*rsqrtf((float)var+1e-5f);
    float sh=cbe[tid]-(float)mean*sc;
    v[tid]=out1[b*32+tid]*sc+sh;
  }
  __syncthreads();
  if (tid<2){
    const float* w=W2+tid*32;
    float a=b2[tid];
    #pragma unroll
    for (int j=0;j<32;j++) a += w[j]*v[j];
    z[tid]=a;
  }
  __syncthreads();
  if (tid<2){
    float m=fmaxf(z[0],z[1]);
    float l=m+logf(expf(z[0]-m)+expf(z[1]-m));
    out[b*2+tid]=z[tid]-l;
  }
}

extern "C" void kernel_launch(void* const* d_in, const int* in_sizes, int n_in,
                              void* d_out, int out_size, void* d_ws, size_t ws_size,
                              hipStream_t stream) {
  (void)in_sizes; (void)n_in; (void)out_size; (void)ws_size;
  const float* x     = (const float*)d_in[0];
  const float* lgw   = (const float*)d_in[1];
  const float* gmask = (const float*)d_in[2];
  const float* fc1   = (const float*)d_in[3];
  const float* fc2   = (const float*)d_in[4];
  const float* saw   = (const float*)d_in[5];
  const float* tril  = (const float*)d_in[6];
  const float* ldW   = (const float*)d_in[7];
  const float* ldb   = (const float*)d_in[8];
  const float* ldg   = (const float*)d_in[9];
  const float* ldbe  = (const float*)d_in[10];
  const float* ld1W  = (const float*)d_in[11];
  const float* ld1b  = (const float*)d_in[12];
  const float* ld1g  = (const float*)d_in[13];
  const float* ld1be = (const float*)d_in[14];
  const float* dW    = (const float*)d_in[15];
  const float* db2   = (const float*)d_in[16];
  const float* dg    = (const float*)d_in[17];
  const float* dbe   = (const float*)d_in[18];
  const float* d1W   = (const float*)d_in[19];
  const float* d1b   = (const float*)d_in[20];
  const float* d1g   = (const float*)d_in[21];
  const float* d1be  = (const float*)d_in[22];
  const float* cW1   = (const float*)d_in[23];
  const float* cb1   = (const float*)d_in[24];
  const float* cgam  = (const float*)d_in[25];
  const float* cbet  = (const float*)d_in[26];
  const float* cW2   = (const float*)d_in[27];
  const float* cb2   = (const float*)d_in[28];
  const int*   edges = (const int*)d_in[29];

  char* ws = (char*)d_ws;
  float*  M     = (float*)(ws + WS_M);
  double* acc   = (double*)(ws + WS_ACC);
  float*  smean = (float*)(ws + WS_SMEAN);
  float*  smax  = (float*)(ws + WS_SMAX);
  float*  catt  = (float*)(ws + WS_CATT);
  float*  Y1    = (float*)(ws + WS_Y1);
  float*  delta = (float*)(ws + WS_DELTA);
  float*  Y2    = (float*)(ws + WS_Y2);
  float*  out1  = (float*)(ws + WS_OUT1);
  float*  out   = (float*)d_out;

  k_front<<<NB + 2, 1024, 0, stream>>>(x, lgw, gmask, tril, edges, fc1, fc2,
                                       catt, M, acc);
  k_wav<<<dim3(NB, 16), 256, 0, stream>>>(x, catt, delta, smean, smax);
  k_gcn1<<<NB, 256, 0, stream>>>(delta, M, smean, smax, saw, ldW, ldb, dW, db2, Y1, acc);
  k_gcn2<<<NB, 256, 0, stream>>>(Y1, M, ldg, ldbe, dg, dbe, ld1W, ld1b, d1W, d1b, Y2, acc);
  k_featcls<<<NB, 64, 0, stream>>>(Y2, ld1g, ld1be, d1g, d1be, cW1, cb1, out1, acc);
  k_cls2<<<NB, 64, 0, stream>>>(out1, cgam, cbet, cW2, cb2, acc, out);
}

// Round 10
// 160.029 us; speedup vs baseline: 1.1506x; 1.0176x over previous
//
#include <hip/hip_runtime.h>
#include <math.h>

#define NB 512
#define NN 64
#define TL 657
#define LV1 328
#define LV2 164
#define LV3 82
#define LV4 41
#define HID 82
#define ST 66      // padded LDS stride for 64x64 matrices

// workspace byte offsets (aliased by liveness)
#define WS_M      0          // 2*4096 f32
#define WS_ACC    32768      // 512 doubles
#define WS_SMEAN  36864
#define WS_SMAX   167936
#define WS_CATT   3373568    // 512*657 f32 -> ends 4719104
#define WS_Y1     682496     // 512*64*32 f32 ends 4876800
#define WS_DELTA  4876800    // 512*64*41 f32 -> ends 10250752
#define WS_Y2     4876800    // aliases delta (dead by gcn2)
#define WS_OUT1   5925376    // 512*32 f32

// accumulator (double) indices
#define ACC_Y1 0
#define ACC_Y2 64
#define ACC_O1 80

__device__ __forceinline__ float sigmoidf_(float v){ return 1.0f/(1.0f+expf(-v)); }

__device__ __forceinline__ void wav_level(float* __restrict__ dst, const float* __restrict__ src,
                                          int outL, int inL, int lane){
  const float DLO[8] = {0.23037781330885523f, 0.7148465705525415f, 0.6308807679295904f,
                        -0.02798376941698385f, -0.18703481171888114f, 0.030841381835986965f,
                        0.032883011666982945f, -0.010597401784997278f};
  for (int k=lane; k<outL; k+=64){
    int i0 = 2*k - 3;
    float a = 0.f;
    #pragma unroll
    for (int j=0;j<8;j++){
      int idx = i0 + j;
      idx = (idx < 0) ? idx + inL : ((idx >= inL) ? idx - inL : idx);
      a += src[idx]*DLO[j];
    }
    dst[k] = a;
  }
}

// 64x64 matmul, 16 waves (1024 threads), wave wv does rows [4wv,4wv+4).
__device__ __forceinline__ void mm16(float* __restrict__ D, int dstride,
                                     const float* __restrict__ A, const float* __restrict__ Bm){
  int tid = threadIdx.x;
  int wv = tid >> 6, lane = tid & 63;
  int i0 = wv*4;
  float a4[4] = {0.f,0.f,0.f,0.f};
  #pragma unroll
  for (int kc=0; kc<4; kc++){
    float bb[16];
    #pragma unroll
    for (int j=0;j<16;j++) bb[j] = Bm[(kc*16+j)*ST + lane];
    #pragma unroll
    for (int i=0;i<4;i++){
      const float2* ar = (const float2*)&A[(i0+i)*ST + kc*16];
      float s0=0.f, s1=0.f;
      #pragma unroll
      for (int j2=0;j2<8;j2++){
        float2 v = ar[j2];
        s0 += v.x*bb[2*j2]; s1 += v.y*bb[2*j2+1];
      }
      a4[i] += s0+s1;
    }
  }
  #pragma unroll
  for (int i=0;i<4;i++) D[(i0+i)*dstride + lane] = a4[i];
}

// ---------------- fused front, 512 blocks x 1024 threads:
//   every block: channel stats + CBAM channel-MLP for batch b = blockIdx.x
//   blocks 0,1 additionally run graph prep FIRST (overlapped with other blocks' stats)
__global__ __launch_bounds__(1024) void k_front(
    const float* __restrict__ x,
    const float* __restrict__ lgw, const float* __restrict__ gmask,
    const float* __restrict__ tril, const int* __restrict__ edges,
    const float* __restrict__ fc1, const float* __restrict__ fc2,
    float* __restrict__ catt_g,
    float* __restrict__ Mout, double* __restrict__ acc)
{
  __shared__ float smem[3*NN*ST];   // 12672 floats
  __shared__ float deg[64], hs[64], dinv[64], wself[64];
  int tid = threadIdx.x;
  int bid = blockIdx.x;
  int wv = tid>>6, lane = tid&63;
  int b = bid;

  if (bid < 2){
    // ---- graph prep: g=0 local, g=1 global ----
    float* Wbuf = smem;
    float* Amat = smem + NN*ST;
    float* P1   = smem + 2*NN*ST;
    int g = bid;
    if (g==0 && tid<512) acc[tid]=0.0;
    for (int e=tid;e<4096;e+=1024){
      float w;
      if (g==0) w = lgw[e];
      else {
        int i=e>>6, j=e&63;
        int aa = (i>j)? i:j, bb = (i>j)? j:i;
        w = tril[aa*(aa+1)/2 + bb] * gmask[e];
      }
      Wbuf[e] = w;
    }
    for (int i=tid;i<NN*ST;i+=1024) Amat[i] = 0.f;
    if (tid<64){ deg[tid]=0.f; hs[tid]=0.f; }
    __syncthreads();
    {
      int e0 = tid*4;
      int runr = edges[e0];
      float runv = 0.f;
      #pragma unroll
      for (int i=0;i<4;i++){
        int e = e0+i;
        int r = edges[e];
        int c = edges[4096+e];
        float w = Wbuf[e];
        if (r != runr){ atomicAdd(&deg[runr], runv); runr = r; runv = 0.f; }
        runv += fabsf(w);
        if (r == c) hs[r] = 1.f;
      }
      atomicAdd(&deg[runr], runv);
    }
    __syncthreads();
    if (tid<64){
      float w_ = (hs[tid] > 0.f) ? 0.f : 1.f;
      float d = deg[tid] + w_;
      dinv[tid] = (d > 0.f) ? rsqrtf(d) : 0.f;
      wself[tid] = w_;
    }
    __syncthreads();
    for (int e=tid;e<4096;e+=1024){
      int r = edges[e], c = edges[4096+e];
      float nm = dinv[r]*Wbuf[e]*dinv[c];
      atomicAdd(&Amat[c*ST+r], nm);
    }
    __syncthreads();
    if (tid<64) Amat[tid*ST+tid] += dinv[tid]*wself[tid]*dinv[tid];
    __syncthreads();
    mm16(P1,   ST, Amat, Amat); __syncthreads();   // A^2
    mm16(Wbuf, ST, P1,   P1);   __syncthreads();   // A^4
    mm16(&Mout[g*4096], 64, Wbuf, Amat);           // A^5
    __syncthreads();   // smem dead; reuse for stats below
  }

  // ---- channel stats: wave wv streams rows 4wv..4wv+3 ----
  {
    float s[11], m[11];
    #pragma unroll
    for (int i=0;i<11;i++){ s[i]=0.f; m[i]=-INFINITY; }
    const float* xb = x + (size_t)b*NN*TL;
    for (int r=0;r<4;r++){
      const float* row = xb + (size_t)(wv*4 + r)*TL;
      #pragma unroll
      for (int i=0;i<11;i++){
        int t = lane + 64*i;
        if (t < TL){
          float v = row[t];
          s[i] += v; m[i] = fmaxf(m[i], v);
        }
      }
    }
    // tree merge of 16 wave-partials (slots of 1328 floats)
    for (int step=8; step>=1; step>>=1){
      if (wv >= step && wv < 2*step){
        float* bs = smem + (wv-step)*1328;
        #pragma unroll
        for (int i=0;i<11;i++){
          int t = lane + 64*i;
          if (t<TL){ bs[t] = s[i]; bs[664+t] = m[i]; }
        }
      }
      __syncthreads();
      if (wv < step){
        float* bs = smem + wv*1328;
        #pragma unroll
        for (int i=0;i<11;i++){
          int t = lane + 64*i;
          if (t<TL){ s[i] += bs[t]; m[i] = fmaxf(m[i], bs[664+t]); }
        }
      }
      __syncthreads();
    }
    float* cs = smem;          // [657]
    float* cm = smem + 664;    // [657]
    float* h  = smem + 1400;   // [82]
    if (wv==0){
      #pragma unroll
      for (int i=0;i<11;i++){
        int t = lane + 64*i;
        if (t<TL){ cs[t] = s[i]; cm[t] = m[i]; }
      }
    }
    __syncthreads();
    // MLP layer 1: wave per output row of fc1 (coalesced)
    for (int o=wv; o<HID; o+=16){
      const float* fr = fc1 + (size_t)o*TL;
      float a = 0.f, bm = 0.f;
      #pragma unroll
      for (int i=0;i<11;i++){
        int c = lane + 64*i;
        if (c < TL){
          float f = fr[c];
          a += f*cs[c]; bm += f*cm[c];
        }
      }
      #pragma unroll
      for (int off=32;off;off>>=1){
        a  += __shfl_xor(a,off);
        bm += __shfl_xor(bm,off);
      }
      if (lane==0)
        h[o] = fmaxf(a*(1.0f/64.0f),0.f) + fmaxf(bm,0.f);
    }
    __syncthreads();
    // MLP layer 2: thread per output channel c, fc2 row contiguous (float2)
    if (tid < TL){
      const float2* fr = (const float2*)(fc2 + (size_t)tid*HID);
      float a0=0.f, a1=0.f;
      #pragma unroll
      for (int u2=0;u2<41;u2++){
        float2 v = fr[u2];
        a0 += v.x*h[2*u2]; a1 += v.y*h[2*u2+1];
      }
      catt_g[(size_t)b*TL + tid] = sigmoidf_(a0+a1);
    }
  }
}

// ---------------- wavelet cascade + spatial stats: grid (512,16), one row per wave ----------------
__global__ __launch_bounds__(256) void k_wav(
    const float* __restrict__ x, const float* __restrict__ catt_g,
    float* __restrict__ delta, float* __restrict__ smean, float* __restrict__ smax)
{
  __shared__ float catt[TL];
  __shared__ float yb[4][TL];
  __shared__ float o1b[4][LV1];
  __shared__ float o2b[4][LV2];
  __shared__ float o3b[4][LV3];
  int tid = threadIdx.x, b = blockIdx.x;
  for (int i=tid;i<TL;i+=256) catt[i] = catt_g[(size_t)b*TL + i];
  __syncthreads();
  int wv = tid>>6, lane = tid&63;
  int n = blockIdx.y*4 + wv;
  float* y  = yb[wv];
  float* p1 = o1b[wv];
  float* p2 = o2b[wv];
  float* p3 = o3b[wv];
  const float DLO[8] = {0.23037781330885523f, 0.7148465705525415f, 0.6308807679295904f,
                        -0.02798376941698385f, -0.18703481171888114f, 0.030841381835986965f,
                        0.032883011666982945f, -0.010597401784997278f};
  const float* row = x + ((size_t)b*NN + n)*TL;
  float ls = 0.f, lm = -INFINITY;
  #pragma unroll
  for (int i=0;i<11;i++){
    int t = lane + 64*i;
    if (t < TL){
      float v = row[t]*catt[t];
      y[t] = v; ls += v; lm = fmaxf(lm,v);
    }
  }
  #pragma unroll
  for (int off=32;off;off>>=1){
    ls += __shfl_xor(ls,off);
    lm = fmaxf(lm, __shfl_xor(lm,off));
  }
  if (lane==0){ smean[b*NN+n] = ls*(1.0f/657.0f); smax[b*NN+n] = lm; }
  wav_level(p1, y,  LV1, TL,  lane);
  wav_level(p2, p1, LV2, LV1, lane);
  wav_level(p3, p2, LV3, LV2, lane);
  if (lane < LV4){
    int i0 = 2*lane - 3;
    float a = 0.f;
    #pragma unroll
    for (int j=0;j<8;j++){
      int idx = i0 + j;
      idx = (idx < 0) ? idx + LV3 : ((idx >= LV3) ? idx - LV3 : idx);
      a += p3[idx]*DLO[j];
    }
    delta[((size_t)b*NN + n)*LV4 + lane] = a;
  }
}

// ---------------- GCN block 1 (+ fused spatial attention scale) ----------------
__global__ __launch_bounds__(256) void k_gcn1(
  const float* __restrict__ delta, const float* __restrict__ Mmat,
  const float* __restrict__ smean, const float* __restrict__ smax,
  const float* __restrict__ saw,
  const float* __restrict__ ldW, const float* __restrict__ ldb,
  const float* __restrict__ dW, const float* __restrict__ db2,
  float* __restrict__ Y1, double* __restrict__ acc)
{
  __shared__ float Dl[NN*LV4];
  __shared__ float Tt[NN*16];
  __shared__ float Mm[4096];
  __shared__ float Wl[16*LV4];
  __shared__ float satt[NN];
  __shared__ double red[256];
  int tid=threadIdx.x, b=blockIdx.x;
  if (tid < NN){
    float a = 0.f;
    #pragma unroll
    for (int kw=0;kw<7;kw++){
      int w = tid + kw - 3;
      if (0<=w && w<NN) a += smean[b*NN+w]*saw[21+kw] + smax[b*NN+w]*saw[70+kw];
    }
    satt[tid] = sigmoidf_(a);
  }
  __syncthreads();
  const float* ds = delta + (size_t)b*NN*LV4;
  for (int i=tid;i<NN*LV4;i+=256) Dl[i] = ds[i]*satt[i/LV4];
  for (int g=0; g<2; g++){
    const float* Ws = g ? dW : ldW;
    const float* bs = g ? db2 : ldb;
    for (int i=tid;i<16*LV4;i+=256) Wl[i]=Ws[i];
    for (int i=tid;i<4096;i+=256) Mm[i]=Mmat[g*4096+i];
    __syncthreads();
    for (int e=tid;e<NN*16;e+=256){
      int n=e>>4, o=e&15;
      const float* dr=&Dl[n*LV4];
      const float* wr=&Wl[o*LV4];
      float a=0.f;
      #pragma unroll 8
      for (int c=0;c<LV4;c++) a += dr[c]*wr[c];
      Tt[e]=a;
    }
    __syncthreads();
    float bias = bs[tid&15];
    float ps=0.f, pq=0.f;
    for (int m=0;m<4;m++){
      int e=tid+256*m;
      int n=e>>4, o=e&15;
      float a=bias;
      #pragma unroll 8
      for (int k=0;k<64;k++) a += Mm[n*64+k]*Tt[k*16+o];
      Y1[((size_t)b*NN+n)*32 + g*16 + o] = a;
      ps += a; pq += a*a;
    }
    red[tid]=(double)ps;
    __syncthreads();
    if (tid<16){ double t=0; for (int r=tid;r<256;r+=16) t+=red[r]; atomicAdd(&acc[ACC_Y1+g*32+tid], t); }
    __syncthreads();
    red[tid]=(double)pq;
    __syncthreads();
    if (tid<16){ double t=0; for (int r=tid;r<256;r+=16) t+=red[r]; atomicAdd(&acc[ACC_Y1+g*32+16+tid], t); }
    __syncthreads();
  }
}

// ---------------- GCN block 2 ----------------
__global__ __launch_bounds__(256) void k_gcn2(
  const float* __restrict__ Y1, const float* __restrict__ Mmat,
  const float* __restrict__ ldg, const float* __restrict__ ldbe,
  const float* __restrict__ dg, const float* __restrict__ dbe,
  const float* __restrict__ ld1W, const float* __restrict__ ld1b,
  const float* __restrict__ d1W, const float* __restrict__ d1b,
  float* __restrict__ Y2, double* __restrict__ acc)
{
  __shared__ float Yl[NN*32];
  __shared__ float T2[NN*8];
  __shared__ float Mm[2*4096];
  __shared__ float scl[32], sht[32];
  __shared__ double red[256];
  int tid=threadIdx.x, b=blockIdx.x;
  const float* ys = Y1 + (size_t)b*NN*32;
  for (int i=tid;i<NN*32;i+=256) Yl[i]=ys[i];
  for (int i=tid;i<8192;i+=256) Mm[i]=Mmat[i];
  if (tid<32){
    int g=tid>>4, o=tid&15;
    double s=acc[ACC_Y1+g*32+o], q=acc[ACC_Y1+g*32+16+o];
    double mean=s/32768.0;
    double var=q/32768.0 - mean*mean;
    float gam = g? dg[o] : ldg[o];
    float bet = g? dbe[o] : ldbe[o];
    float sc = gam * rsqrtf((float)var + 1e-5f);
    scl[tid]=sc; sht[tid]=bet - (float)mean*sc;
  }
  __syncthreads();
  for (int i=tid;i<NN*32;i+=256){ int c=i&31; Yl[i]=Yl[i]*scl[c]+sht[c]; }
  __syncthreads();
  for (int e=tid;e<NN*8;e+=256){
    int n=e>>3, c=e&7, g=c>>2, p=c&3;
    const float* w = (g? d1W : ld1W) + p*16;
    const float* yr = &Yl[n*32 + g*16];
    float a=0.f;
    #pragma unroll
    for (int o=0;o<16;o++) a += yr[o]*w[o];
    T2[e]=a;
  }
  __syncthreads();
  float ps=0.f,pq=0.f;
  for (int m=0;m<2;m++){
    int e=tid+256*m;
    int n=e>>3, c=e&7, g=c>>2;
    float a = g? d1b[c&3] : ld1b[c&3];
    const float* mr=&Mm[g*4096+n*64];
    #pragma unroll 8
    for (int k=0;k<64;k++) a += mr[k]*T2[k*8+c];
    Y2[((size_t)b*NN+n)*8 + c] = a;
    ps+=a; pq+=a*a;
  }
  red[tid]=(double)ps; __syncthreads();
  if (tid<8){ double t=0; for (int r=tid;r<256;r+=8) t+=red[r]; atomicAdd(&acc[ACC_Y2 + (tid>>2)*8 + (tid&3)], t); }
  __syncthreads();
  red[tid]=(double)pq; __syncthreads();
  if (tid<8){ double t=0; for (int r=tid;r<256;r+=8) t+=red[r]; atomicAdd(&acc[ACC_Y2 + (tid>>2)*8 + 4 + (tid&3)], t); }
}

// ---------------- BN(Y2) -> feat -> cls layer1 ----------------
__global__ __launch_bounds__(64) void k_featcls(
  const float* __restrict__ Y2,
  const float* __restrict__ ld1g, const float* __restrict__ ld1be,
  const float* __restrict__ d1g, const float* __restrict__ d1be,
  const float* __restrict__ W1, const float* __restrict__ b1,
  float* __restrict__ out1, double* __restrict__ acc)
{
  __shared__ float f[128];
  __shared__ float scl[8], sht[8];
  int tid=threadIdx.x, b=blockIdx.x;
  if (tid<8){
    int g=tid>>2, p=tid&3;
    double s=acc[ACC_Y2+g*8+p], q=acc[ACC_Y2+g*8+4+p];
    double mean=s/32768.0;
    double var=q/32768.0-mean*mean;
    float gam = g? d1g[p]:ld1g[p];
    float bet = g? d1be[p]:ld1be[p];
    float sc = gam*rsqrtf((float)var+1e-5f);
    scl[tid]=sc; sht[tid]=bet-(float)mean*sc;
  }
  __syncthreads();
  {
    const float* yr = Y2 + ((size_t)b*NN+tid)*8;
    float lf=0.f, gf=0.f;
    #pragma unroll
    for (int p=0;p<4;p++){
      lf += yr[p]*scl[p]+sht[p];
      gf += yr[4+p]*scl[4+p]+sht[4+p];
    }
    f[2*tid]   = lf*0.25f;
    f[2*tid+1] = gf*0.25f;
  }
  __syncthreads();
  if (tid<32){
    const float* w = W1 + tid*128;
    float a = b1[tid];
    #pragma unroll 4
    for (int m=0;m<128;m++) a += w[m]*f[m];
    out1[b*32+tid]=a;
    atomicAdd(&acc[ACC_O1+tid], (double)a);
    atomicAdd(&acc[ACC_O1+32+tid], (double)(a*a));
  }
}

// ---------------- BN(out1) -> cls layer2 -> log_softmax ----------------
__global__ __launch_bounds__(64) void k_cls2(
  const float* __restrict__ out1,
  const float* __restrict__ cg, const float* __restrict__ cbe,
  const float* __restrict__ W2, const float* __restrict__ b2,
  const double* __restrict__ acc, float* __restrict__ out)
{
  __shared__ float v[32];
  __shared__ float z[2];
  int tid=threadIdx.x, b=blockIdx.x;
  if (tid<32){
    double s=acc[ACC_O1+tid], q=acc[ACC_O1+32+tid];
    double mean=s/512.0;
    double var=q/512.0-mean*mean;
    float sc=cg[tid]*rsqrtf((float)var+1e-5f);
    float sh=cbe[tid]-(float)mean*sc;
    v[tid]=out1[b*32+tid]*sc+sh;
  }
  __syncthreads();
  if (tid<2){
    const float* w=W2+tid*32;
    float a=b2[tid];
    #pragma unroll
    for (int j=0;j<32;j++) a += w[j]*v[j];
    z[tid]=a;
  }
  __syncthreads();
  if (tid<2){
    float m=fmaxf(z[0],z[1]);
    float l=m+logf(expf(z[0]-m)+expf(z[1]-m));
    out[b*2+tid]=z[tid]-l;
  }
}

extern "C" void kernel_launch(void* const* d_in, const int* in_sizes, int n_in,
                              void* d_out, int out_size, void* d_ws, size_t ws_size,
                              hipStream_t stream) {
  (void)in_sizes; (void)n_in; (void)out_size; (void)ws_size;
  const float* x     = (const float*)d_in[0];
  const float* lgw   = (const float*)d_in[1];
  const float* gmask = (const float*)d_in[2];
  const float* fc1   = (const float*)d_in[3];
  const float* fc2   = (const float*)d_in[4];
  const float* saw   = (const float*)d_in[5];
  const float* tril  = (const float*)d_in[6];
  const float* ldW   = (const float*)d_in[7];
  const float* ldb   = (const float*)d_in[8];
  const float* ldg   = (const float*)d_in[9];
  const float* ldbe  = (const float*)d_in[10];
  const float* ld1W  = (const float*)d_in[11];
  const float* ld1b  = (const float*)d_in[12];
  const float* ld1g  = (const float*)d_in[13];
  const float* ld1be = (const float*)d_in[14];
  const float* dW    = (const float*)d_in[15];
  const float* db2   = (const float*)d_in[16];
  const float* dg    = (const float*)d_in[17];
  const float* dbe   = (const float*)d_in[18];
  const float* d1W   = (const float*)d_in[19];
  const float* d1b   = (const float*)d_in[20];
  const float* d1g   = (const float*)d_in[21];
  const float* d1be  = (const float*)d_in[22];
  const float* cW1   = (const float*)d_in[23];
  const float* cb1   = (const float*)d_in[24];
  const float* cgam  = (const float*)d_in[25];
  const float* cbet  = (const float*)d_in[26];
  const float* cW2   = (const float*)d_in[27];
  const float* cb2   = (const float*)d_in[28];
  const int*   edges = (const int*)d_in[29];

  char* ws = (char*)d_ws;
  float*  M     = (float*)(ws + WS_M);
  double* acc   = (double*)(ws + WS_ACC);
  float*  smean = (float*)(ws + WS_SMEAN);
  float*  smax  = (float*)(ws + WS_SMAX);
  float*  catt  = (float*)(ws + WS_CATT);
  float*  Y1    = (float*)(ws + WS_Y1);
  float*  delta = (float*)(ws + WS_DELTA);
  float*  Y2    = (float*)(ws + WS_Y2);
  float*  out1  = (float*)(ws + WS_OUT1);
  float*  out   = (float*)d_out;

  k_front<<<NB, 1024, 0, stream>>>(x, lgw, gmask, tril, edges, fc1, fc2,
                                   catt, M, acc);
  k_wav<<<dim3(NB, 16), 256, 0, stream>>>(x, catt, delta, smean, smax);
  k_gcn1<<<NB, 256, 0, stream>>>(delta, M, smean, smax, saw, ldW, ldb, dW, db2, Y1, acc);
  k_gcn2<<<NB, 256, 0, stream>>>(Y1, M, ldg, ldbe, dg, dbe, ld1W, ld1b, d1W, d1b, Y2, acc);
  k_featcls<<<NB, 64, 0, stream>>>(Y2, ld1g, ld1be, d1g, d1be, cW1, cb1, out1, acc);
  k_cls2<<<NB, 64, 0, stream>>>(out1, cgam, cbet, cW2, cb2, acc, out);
}